// Round 10
// baseline (3351.032 us; speedup 1.0000x reference)
//
#include <hip/hip_runtime.h>
#include <cstdint>

// LSTM B=4096, T=512, D=H=25, 3 layers + MLP head + softmax.
// R10: R9's verified MFMA numerics (f16 hi + 4096*lo, 3-term, interleaved-M
// so gates are lane-local), re-parallelized for latency hiding:
//   8 waves/block: waves 0..6 = one M-tile each (16 gate-rows), wave 7 = stager.
//   W frags per wave = 4 x f16x8 = 16 VGPRs, REGISTER-resident (R9 streamed
//   28 b128/step from LDS). Per step per compute wave: 4 ds_read_b128 (XH) +
//   6 MFMA + lane-local update + 2 ds_write_b16. Stager owns ALL global
//   traffic (x_t / ws h-sequence), 2-step-deep register prefetch.
//   Parity double-buffered XH[2][16][80] f16 (hi,lo planes), ONE lgkmcnt-only
//   barrier per step. Layers sequential via ws packed {hi,lo} u32.
//   256 blocks x 512 thr = 8 waves/CU = 2/SIMD.

typedef _Float16 f16;
typedef f16  f16x8 __attribute__((ext_vector_type(8)));
typedef float f32x4 __attribute__((ext_vector_type(4)));

#define NT 512
#define ND 25
#define NB 16
#define LOSCALE 4096.0f
#define INVLO   2.44140625e-4f

__device__ __forceinline__ float exp2f_(float x){ return __builtin_amdgcn_exp2f(x); }
__device__ __forceinline__ float rcpf_(float x){ return __builtin_amdgcn_rcpf(x); }
__device__ __forceinline__ float sigf(float x){ return rcpf_(1.f + exp2f_(-1.442695041f*x)); }
__device__ __forceinline__ float tanhf_(float x){ return fmaf(2.f, rcpf_(1.f + exp2f_(-2.885390082f*x)), -1.f); }
__device__ __forceinline__ unsigned short f16b(f16 h){ union{f16 h; unsigned short s;} u; u.h=h; return u.s; }
__device__ __forceinline__ f16 b2f16(unsigned short s){ union{f16 h; unsigned short s;} u; u.s=s; return u.h; }

#define MFMA(a,b,c) __builtin_amdgcn_mfma_f32_16x16x32_f16((a),(b),(c),0,0,0)
#define LDSBAR() asm volatile("s_waitcnt lgkmcnt(0)\n\ts_barrier" ::: "memory")

__global__ __launch_bounds__(512, 2)
void lstm10(const float* __restrict__ xin, const float* __restrict__ Wih,
            const float* __restrict__ Whh, const float* __restrict__ bih,
            const float* __restrict__ bhh, const float* __restrict__ W1,
            const float* __restrict__ b1,  const float* __restrict__ W2,
            const float* __restrict__ b2,  float* __restrict__ out,
            uint32_t* __restrict__ ws)
{
    // XH row (per batch): [x(25) | h(25) | 0(13) | bias-col=1.0 @63 | pad..79]
    __shared__ __align__(16) f16 XH_H[2][NB][80];
    __shared__ __align__(16) f16 XH_L[2][NB][80];
    __shared__ __align__(16) float hfin[NB][28];

    const int tid  = threadIdx.x;
    const int wid  = tid >> 6;
    const int lane = tid & 63;
    const int bq   = lane & 15;
    const int lg   = lane >> 4;
    const int bb   = blockIdx.x * NB;

    // one-time zero init + bias column
    for (int i = tid; i < 2*NB*80; i += 512) {
        (&XH_H[0][0][0])[i] = (f16)0.f;
        (&XH_L[0][0][0])[i] = (f16)0.f;
    }
    __syncthreads();
    if (tid < 2*NB) XH_H[tid>>4][tid&15][63] = (f16)1.f;

    if (wid < 7) {
        // ================= COMPUTE WAVE (M-tile mt = wid) =================
        const int mt = wid;
        const int rp = mt*16 + bq;                 // interleaved gate-row
        const bool wvalid = rp < 100;
        const int ro = (rp & 3)*ND + (rp >> 2);    // torch-order row
        const int uD = mt*4 + lg;                  // unit owned by this lane (D-frag)
        const bool dvalid = uD < ND;
        float h = 0.f;

        for (int l = 0; l < 3; ++l) {
            // ---- W fragments into registers (hi + 4096*lo f16) ----
            const float* wri = Wih + ((size_t)l*100 + ro)*ND;
            const float* wrh = Whh + ((size_t)l*100 + ro)*ND;
            const float bsum = wvalid ? (bih[l*100+ro] + bhh[l*100+ro]) : 0.f;
            f16x8 wh0, wh1, wl0, wl1;
#pragma unroll
            for (int kt = 0; kt < 2; ++kt) {
                f16x8 vh, vl;
#pragma unroll
                for (int i = 0; i < 8; ++i) {
                    const int k = kt*32 + lg*8 + i;
                    float w = 0.f;
                    if (wvalid) {
                        if (k < ND)            w = wri[k];
                        else if (k < 2*ND)     w = wrh[k-ND];
                        else if (k == 63)      w = bsum;
                    }
                    const f16 hi = (f16)w;
                    vh[i] = hi; vl[i] = (f16)((w - (float)hi)*LOSCALE);
                }
                if (kt == 0) { wh0 = vh; wl0 = vl; } else { wh1 = vh; wl1 = vl; }
            }

            __syncthreads();   // (a) prev-layer ws stores drained (full barrier)
            if (dvalid) { XH_H[0][bq][ND+uD] = (f16)0.f; XH_L[0][bq][ND+uD] = (f16)0.f; }
            float c = 0.f; h = 0.f;
            __syncthreads();   // (b) layer init visible (stager wrote x_0)

            for (int t = 0; t < NT; ++t) {
                const int p = t & 1;
                const f16x8 bh0 = *(const f16x8*)&XH_H[p][bq][lg*8];
                const f16x8 bh1 = *(const f16x8*)&XH_H[p][bq][32 + lg*8];
                const f16x8 bl0 = *(const f16x8*)&XH_L[p][bq][lg*8];
                const f16x8 bl1 = *(const f16x8*)&XH_L[p][bq][32 + lg*8];
                f32x4 d1 = {0,0,0,0}, d2 = {0,0,0,0};
                d1 = MFMA(wh0, bh0, d1); d1 = MFMA(wh1, bh1, d1);
                d2 = MFMA(wh0, bl0, d2); d2 = MFMA(wh1, bl1, d2);
                d2 = MFMA(wl0, bh0, d2); d2 = MFMA(wl1, bh1, d2);
                const f32x4 dd = d1 + d2 * INVLO;

                const float gi = sigf(dd[0]);
                const float gf = sigf(dd[1]);
                const float gg = tanhf_(dd[2]);
                const float go = sigf(dd[3]);
                c = fmaf(gf, c, gi*gg);
                h = go * tanhf_(c);

                if (dvalid) {
                    const f16 hi = (f16)h;
                    const f16 lo = (f16)((h - (float)hi)*LOSCALE);
                    XH_H[p^1][bq][ND+uD] = hi;
                    XH_L[p^1][bq][ND+uD] = lo;
                    if (l < 2)
                        ws[((size_t)(bb+bq)*NT + t)*ND + uD] =
                            (uint32_t)f16b(hi) | ((uint32_t)f16b(lo) << 16);
                }
                LDSBAR();
            }
        }
        if (dvalid) hfin[bq][uD] = h;   // final-layer h for the head
    } else {
        // ======================= STAGER WAVE =======================
        // lane+64j -> (batch bj, unit uj), j = 0..6 (400 valid pairs)
        bool jv[7]; int eoff[7], loff[7];
#pragma unroll
        for (int j = 0; j < 7; ++j) {
            const int idx = lane + 64*j;
            jv[j] = idx < NB*ND;
            const int bj = jv[j] ? idx / ND : 0;
            const int uj = jv[j] ? idx % ND : 0;
            eoff[j] = bj * (NT*ND) + uj;   // element offset in batch-tile
            loff[j] = bj * 80 + uj;        // f16 offset within one parity plane
        }

        for (int l = 0; l < 3; ++l) {
            const bool isl0 = (l == 0);
            const float*    sx = xin + (size_t)bb*NT*ND;
            const uint32_t* sw = ws  + (size_t)bb*NT*ND;

            __syncthreads();   // (a)
            float fc[7], fn[7]; uint32_t pc[7], pn[7];
#pragma unroll
            for (int j = 0; j < 7; ++j) {
                fc[j] = fn[j] = 0.f; pc[j] = pn[j] = 0u;
                if (jv[j]) {
                    if (isl0) {
                        const float v = sx[eoff[j]];              // x_0
                        const f16 hi = (f16)v;
                        XH_H[0][0][loff[j]] = hi;
                        XH_L[0][0][loff[j]] = (f16)((v - (float)hi)*LOSCALE);
                        fc[j] = sx[eoff[j] + ND];                 // x_1
                        fn[j] = sx[eoff[j] + 2*ND];               // x_2
                    } else {
                        const uint32_t pk = sw[eoff[j]];
                        XH_H[0][0][loff[j]] = b2f16((unsigned short)(pk & 0xffffu));
                        XH_L[0][0][loff[j]] = b2f16((unsigned short)(pk >> 16));
                        pc[j] = sw[eoff[j] + ND];
                        pn[j] = sw[eoff[j] + 2*ND];
                    }
                }
            }
            __syncthreads();   // (b)

            for (int t = 0; t < NT; ++t) {
                const int q = (t & 1) ^ 1;
                if (t + 1 < NT) {
#pragma unroll
                    for (int j = 0; j < 7; ++j) {
                        if (jv[j]) {
                            if (isl0) {
                                const float v = fc[j];
                                const f16 hi = (f16)v;
                                XH_H[q][0][loff[j]] = hi;
                                XH_L[q][0][loff[j]] = (f16)((v - (float)hi)*LOSCALE);
                                fc[j] = fn[j];
                                if (t + 3 < NT) fn[j] = sx[eoff[j] + (size_t)(t+3)*ND];
                            } else {
                                const uint32_t pk = pc[j];
                                XH_H[q][0][loff[j]] = b2f16((unsigned short)(pk & 0xffffu));
                                XH_L[q][0][loff[j]] = b2f16((unsigned short)(pk >> 16));
                                pc[j] = pn[j];
                                if (t + 3 < NT) pn[j] = sw[eoff[j] + (size_t)(t+3)*ND];
                            }
                        }
                    }
                }
                LDSBAR();
            }
        }
    }

    __syncthreads();
    // ---- head: relu(h W1^T + b1) W2^T + b2, softmax(14). Wave 0, lane=batch ----
    if (wid == 0 && lane < NB) {
        const int b = lane;
        float u1[16];
#pragma unroll
        for (int r = 0; r < 16; ++r) {
            float acc = b1[r];
#pragma unroll
            for (int d = 0; d < ND; ++d) acc = fmaf(W1[r*ND + d], hfin[b][d], acc);
            u1[r] = fmaxf(acc, 0.f);
        }
        float lgt[14]; float m = -1e30f;
#pragma unroll
        for (int r = 0; r < 14; ++r) {
            float acc = b2[r];
#pragma unroll
            for (int k2 = 0; k2 < 16; ++k2) acc = fmaf(W2[r*16 + k2], u1[k2], acc);
            lgt[r] = acc; m = fmaxf(m, acc);
        }
        float s = 0.f;
#pragma unroll
        for (int r = 0; r < 14; ++r) { lgt[r] = exp2f_(1.442695041f*(lgt[r]-m)); s += lgt[r]; }
        const float inv = rcpf_(s);
#pragma unroll
        for (int r = 0; r < 14; ++r) out[(size_t)(bb+b)*14 + r] = lgt[r]*inv;
    }
}

extern "C" void kernel_launch(void* const* d_in, const int* in_sizes, int n_in,
                              void* d_out, int out_size, void* d_ws, size_t ws_size,
                              hipStream_t stream)
{
    const float* x   = (const float*)d_in[0];
    const float* Wih = (const float*)d_in[1];
    const float* Whh = (const float*)d_in[2];
    const float* bih = (const float*)d_in[3];
    const float* bhh = (const float*)d_in[4];
    const float* W1  = (const float*)d_in[5];
    const float* b1  = (const float*)d_in[6];
    const float* W2  = (const float*)d_in[7];
    const float* b2  = (const float*)d_in[8];
    float*    outp = (float*)d_out;
    uint32_t* ws   = (uint32_t*)d_ws;   // 4096*512*25*4 B = 210 MB packed {hi,lo}

    dim3 grid(4096 / NB), block(512);   // 256 blocks x 8 waves
    hipLaunchKernelGGL(lstm10, grid, block, 0, stream,
                       x, Wih, Whh, bih, bhh, W1, b1, W2, b2, outp, ws);
}